// Round 6
// baseline (307.605 us; speedup 1.0000x reference)
//
#include <hip/hip_runtime.h>

#define Bsz 4096
#define Tlen 512
#define IND 18
#define HD 12

typedef float v4f __attribute__((ext_vector_type(4)));

__device__ __forceinline__ float sigmoid_f(float x) {
  return __builtin_amdgcn_rcpf(1.0f + __expf(-x));
}
__device__ __forceinline__ float tanh_f(float x) {
  // tanh(x) = 1 - 2/(1+exp(2x)); saturates correctly at +-inf
  return 1.0f - 2.0f * __builtin_amdgcn_rcpf(1.0f + __expf(2.0f * x));
}

// 3-stage producer pipeline, 12 waves/block (768 thr) covering 16 batches.
// Wave type = wid%3: A (layer0), B (gi1 = W_ih1*h1), C (h2 recurrence + FC).
// HW places wave i on SIMD i%4, so each SIMD hosts exactly {A,B,C}: 3
// waves/SIMD with staggered phases -> stalls of one wave covered by the
// others. One s_barrier per tick; C runs 2 ticks behind A. 514 ticks.
// h1: A->B via double-buffered LDS; gi1: B->C likewise (parity-disjoint
// slots each tick). 256 blocks = 1 block/CU.
extern "C" __global__ void __launch_bounds__(768, 3) gru2_pipe3(
    const float* __restrict__ x,
    const float* __restrict__ wih0, const float* __restrict__ whh0,
    const float* __restrict__ bih0, const float* __restrict__ bhh0,
    const float* __restrict__ wih1, const float* __restrict__ whh1,
    const float* __restrict__ bih1, const float* __restrict__ bhh1,
    const float* __restrict__ fcw, const float* __restrict__ fcb,
    float* __restrict__ out)
{
  const int tid    = threadIdx.x;
  const int lane15 = tid & 15;
  const int g      = (tid >> 4) & 3;      // 16-lane group within wave
  const int wid    = tid >> 6;            // 0..11
  const int typ    = wid % 3;             // A=0, B=1, C=2
  const int bb     = (wid / 3) * 4 + g;   // batch within block 0..15
  const int b      = blockIdx.x * 16 + bb;
  const int j      = (lane15 < HD) ? lane15 : (HD - 1);
  const bool act   = (lane15 < HD);

  __shared__ float h1buf[2][16][16];      // A -> B (double-buffered by tick parity)
  __shared__ float gi1buf[2][16][48];     // B -> C (stride-16 planes r/z/n)
  __shared__ float h2buf[16][16];         // C-private broadcast slot

  if (typ == 0) {
    // ---------------- A: layer 0 ----------------
    float wr[IND], wz[IND], wn[IND];
#pragma unroll
    for (int k = 0; k < IND; ++k) {
      wr[k] = wih0[(0 * HD + j) * IND + k];
      wz[k] = wih0[(1 * HD + j) * IND + k];
      wn[k] = wih0[(2 * HD + j) * IND + k];
    }
    float ur[HD], uz[HD], un[HD];
#pragma unroll
    for (int k = 0; k < HD; ++k) {
      ur[k] = whh0[(0 * HD + j) * HD + k];
      uz[k] = whh0[(1 * HD + j) * HD + k];
      un[k] = whh0[(2 * HD + j) * HD + k];
    }
    const float br = bih0[j] + bhh0[j];
    const float bz = bih0[HD + j] + bhh0[HD + j];
    const float bi = bih0[2 * HD + j];
    const float bh = bhh0[2 * HD + j];

    v4f hv[3];
    hv[0] = (v4f){0.f,0.f,0.f,0.f}; hv[1] = (v4f){0.f,0.f,0.f,0.f}; hv[2] = (v4f){0.f,0.f,0.f,0.f};
    float h1 = 0.f;
    const float2* xp2 = (const float2*)(x + (size_t)b * Tlen * IND);
    float xn[IND];
    float ar, az, an;
    {
#pragma unroll
      for (int i = 0; i < 9; ++i) { float2 v = xp2[i]; xn[2*i] = v.x; xn[2*i+1] = v.y; }
      ar = br; az = bz; an = bi;   // x-projections for t=0
#pragma unroll
      for (int k = 0; k < IND; ++k) { ar += xn[k]*wr[k]; az += xn[k]*wz[k]; an += xn[k]*wn[k]; }
#pragma unroll
      for (int i = 0; i < 9; ++i) { float2 v = xp2[9+i]; xn[2*i] = v.x; xn[2*i+1] = v.y; }  // x[1]
    }
    const float2* xq = xp2 + 18;  // points at x[2]

    for (int s = 0; s < Tlen + 2; ++s) {
      if (s < Tlen) {
        float hr = ar, hz = az, hn = bh;
#pragma unroll
        for (int k = 0; k < HD; ++k) {
          float h = hv[k >> 2][k & 3];
          hr += h * ur[k]; hz += h * uz[k]; hn += h * un[k];
        }
        float r = sigmoid_f(hr), zz = sigmoid_f(hz);
        float n = tanh_f(an + r * hn);
        h1 = n + zz * (h1 - n);
        float* sp = &h1buf[s & 1][bb][0];
        if (act) sp[j] = h1;
        // readback (own next-step hh0 input); consumed after x-projections
        v4f a0 = *(const v4f*)(sp + 0);
        v4f a1 = *(const v4f*)(sp + 4);
        v4f a2 = *(const v4f*)(sp + 8);
        if (s + 1 < Tlen) {
          ar = br; az = bz; an = bi;
#pragma unroll
          for (int k = 0; k < IND; ++k) { ar += xn[k]*wr[k]; az += xn[k]*wz[k]; an += xn[k]*wn[k]; }
          if (s + 2 < Tlen) {
#pragma unroll
            for (int i = 0; i < 9; ++i) { float2 v = xq[i]; xn[2*i] = v.x; xn[2*i+1] = v.y; }
            xq += 9;
          }
        }
        hv[0] = a0; hv[1] = a1; hv[2] = a2;
      }
      asm volatile("s_waitcnt lgkmcnt(0)" ::: "memory");
      __builtin_amdgcn_s_barrier();
      asm volatile("" ::: "memory");
    }
  } else if (typ == 1) {
    // ---------------- B: gi1 = W_ih1 * h1 ----------------
    float vr[HD], vz[HD], vn[HD];
#pragma unroll
    for (int k = 0; k < HD; ++k) {
      vr[k] = wih1[(0 * HD + j) * HD + k];
      vz[k] = wih1[(1 * HD + j) * HD + k];
      vn[k] = wih1[(2 * HD + j) * HD + k];
    }
    for (int s = 0; s < Tlen + 2; ++s) {
      if (s >= 1 && s <= Tlen) {
        const float* hp = &h1buf[(s - 1) & 1][bb][0];
        v4f a0 = *(const v4f*)(hp + 0);
        v4f a1 = *(const v4f*)(hp + 4);
        v4f a2 = *(const v4f*)(hp + 8);
        float gr = 0.f, gz = 0.f, gn = 0.f;
#pragma unroll
        for (int k = 0; k < HD; ++k) {
          float h = (k < 4) ? a0[k] : (k < 8) ? a1[k - 4] : a2[k - 8];
          gr += h * vr[k]; gz += h * vz[k]; gn += h * vn[k];
        }
        float* gp = &gi1buf[(s - 1) & 1][bb][0];
        if (act) { gp[j] = gr; gp[16 + j] = gz; gp[32 + j] = gn; }
      }
      asm volatile("s_waitcnt lgkmcnt(0)" ::: "memory");
      __builtin_amdgcn_s_barrier();
      asm volatile("" ::: "memory");
    }
  } else {
    // ---------------- C: h2 recurrence + FC ----------------
    float ur[HD], uz[HD], un[HD], fw[HD];
#pragma unroll
    for (int k = 0; k < HD; ++k) {
      ur[k] = whh1[(0 * HD + j) * HD + k];
      uz[k] = whh1[(1 * HD + j) * HD + k];
      un[k] = whh1[(2 * HD + j) * HD + k];
      fw[k] = fcw[k];
    }
    const float br1 = bih1[j] + bhh1[j];
    const float bz1 = bih1[HD + j] + bhh1[HD + j];
    const float bi1 = bih1[2 * HD + j];
    const float bh1 = bhh1[2 * HD + j];
    const float fb  = fcb[0];

    v4f hw[3];
    hw[0] = (v4f){0.f,0.f,0.f,0.f}; hw[1] = (v4f){0.f,0.f,0.f,0.f}; hw[2] = (v4f){0.f,0.f,0.f,0.f};
    float h2 = 0.f;
    float* op = out + (size_t)b * Tlen;

    for (int s = 0; s < Tlen + 2; ++s) {
      if (s >= 2) {
        const float* gp = &gi1buf[s & 1][bb][0];   // gi1[s-2]
        float gr = gp[j], gz = gp[16 + j], gn = gp[32 + j];
        // hh1 + FC dots on hw = h2[s-3] (covers the gi1 read latency)
        float hr = br1, hz = bz1, hn = bh1, oc = fb;
#pragma unroll
        for (int k = 0; k < HD; ++k) {
          float h = hw[k >> 2][k & 3];
          hr += h * ur[k]; hz += h * uz[k]; hn += h * un[k]; oc += h * fw[k];
        }
        if (s >= 3) { if (lane15 == 0) *op = oc; ++op; }
        float r1 = sigmoid_f(gr + hr), z1 = sigmoid_f(gz + hz);
        float n1 = tanh_f(gn + bi1 + r1 * hn);
        h2 = n1 + z1 * (h2 - n1);
        float* sq = &h2buf[bb][0];
        if (act) sq[j] = h2;
        hw[0] = *(const v4f*)(sq + 0);
        hw[1] = *(const v4f*)(sq + 4);
        hw[2] = *(const v4f*)(sq + 8);
      }
      asm volatile("s_waitcnt lgkmcnt(0)" ::: "memory");
      __builtin_amdgcn_s_barrier();
      asm volatile("" ::: "memory");
    }
    // epilogue: FC on h2[Tlen-1]
    float oc = fb;
#pragma unroll
    for (int k = 0; k < HD; ++k) oc += hw[k >> 2][k & 3] * fw[k];
    if (lane15 == 0) *op = oc;
  }
}

extern "C" void kernel_launch(void* const* d_in, const int* in_sizes, int n_in,
                              void* d_out, int out_size, void* d_ws, size_t ws_size,
                              hipStream_t stream) {
  (void)in_sizes; (void)n_in; (void)d_ws; (void)ws_size; (void)out_size;
  const float* x    = (const float*)d_in[0];
  const float* wih0 = (const float*)d_in[1];
  const float* whh0 = (const float*)d_in[2];
  const float* bih0 = (const float*)d_in[3];
  const float* bhh0 = (const float*)d_in[4];
  const float* wih1 = (const float*)d_in[5];
  const float* whh1 = (const float*)d_in[6];
  const float* bih1 = (const float*)d_in[7];
  const float* bhh1 = (const float*)d_in[8];
  const float* fcw  = (const float*)d_in[9];
  const float* fcb  = (const float*)d_in[10];
  float* out = (float*)d_out;

  hipLaunchKernelGGL(gru2_pipe3, dim3(Bsz / 16), dim3(768), 0, stream,
                     x, wih0, whh0, bih0, bhh0, wih1, whh1, bih1, bhh1, fcw, fcb, out);
}